// Round 5
// baseline (464.626 us; speedup 1.0000x reference)
//
#include <hip/hip_runtime.h>
#include <stdint.h>

#define CDIM   4096
#define S_N    3355443
#define R_N    1048576
#define N1     (S_N + R_N)                 // 4404019 contributions
#define TILE   4096
#define WPT    (TILE / 256)                // 16 elements per thread
#define NTILES ((N1 + TILE - 1) / TILE)    // 1076
#define NPAD   (NTILES * TILE)             // 4407296
#define SR_CH  ((NTILES + 255) / 256)      // 5 row entries per thread in scanrows
#define PAD_KEY 0xFFFFFFu
#define PAD_VAL 0xFFFFFFFFu                // impossible value bits (sums are >= +0)
#define SENT  (((uint64_t)PAD_KEY << 32) | (uint64_t)PAD_VAL)

// Exclusive block-wide scan over 256 threads (4 waves). Contains syncthreads.
static __device__ __forceinline__ unsigned blockScanExcl(unsigned v, unsigned t,
                                                         unsigned* lw, unsigned* tot){
  unsigned lane = t & 63u, w = t >> 6;
  unsigned x = v;
  #pragma unroll
  for (int off = 1; off < 64; off <<= 1){
    unsigned y = __shfl_up(x, off, 64);
    if (lane >= (unsigned)off) x += y;
  }
  if (lane == 63u) lw[w] = x;
  __syncthreads();
  unsigned woff = 0;
  for (unsigned i = 0; i < w; i++) woff += lw[i];
  *tot = lw[0] + lw[1] + lw[2] + lw[3];
  __syncthreads();
  return x + woff - v;
}

// Build packed contributions: high32 = key, low32 = value bits. Samples first,
// then decayed buffer entries, then padding -> stable sort preserves
// segment_sum's accumulation order exactly. FUSED: pass-1 LDS histogram
// (shift 32 => key low byte) + coalesced column write (NO global atomics).
__global__ __launch_bounds__(256) void k_build(const int* __restrict__ sidx,
                                               const int* __restrict__ ridx,
                                               const float* __restrict__ rval,
                                               const float* __restrict__ grad,
                                               uint64_t* __restrict__ A,
                                               unsigned* __restrict__ gh){
  __shared__ unsigned h[256];
  unsigned t = threadIdx.x;
  h[t] = 0; __syncthreads();
  size_t base = (size_t)blockIdx.x * TILE;
  #pragma unroll
  for (int r = 0; r < WPT; r++){
    unsigned i = (unsigned)(base + (size_t)r*256 + t);
    uint32_t key, vb;
    if (i < S_N){
      key = (uint32_t)sidx[i];
      vb  = __float_as_uint(fabsf(grad[i]));
    } else if (i < N1){
      unsigned j = i - S_N;
      int2 rc = ((const int2* __restrict__)ridx)[j];
      key = (uint32_t)(rc.x * CDIM + rc.y);
      const float ADJF = (float)(1.0 - (3355443.0 / 16777216.0) * (1.0 - 0.95));
      vb = __float_as_uint(ADJF * rval[j]);
    } else {
      key = PAD_KEY; vb = PAD_VAL;
    }
    A[i] = ((uint64_t)key << 32) | (uint64_t)vb;
    atomicAdd(&h[key & 0xFFu], 1u);        // LDS atomic only
  }
  __syncthreads();
  gh[t * NTILES + blockIdx.x] = h[t];
}

// Per-tile 256-bin histogram of digit (e >> shift) & 0xFF. Layout [digit][tile].
__global__ __launch_bounds__(256) void k_hist(const uint64_t* __restrict__ in, unsigned shift,
                                              unsigned* __restrict__ gh){
  __shared__ unsigned h[256];
  unsigned t = threadIdx.x;
  h[t] = 0; __syncthreads();
  size_t base = (size_t)blockIdx.x * TILE;
  #pragma unroll
  for (int r = 0; r < WPT; r++){
    uint64_t e = in[base + (size_t)r*256 + t];
    atomicAdd(&h[(unsigned)((e >> shift) & 0xFF)], 1u);
  }
  __syncthreads();
  gh[t * NTILES + blockIdx.x] = h[t];
}

// Histogram with sentinel synthesis for i >= nsyn[0]: elements beyond the
// live prefix are counted as digit 255 without touching memory. Tail tiles
// write their (constant) column and return.
__global__ __launch_bounds__(256) void k_hist_syn(const uint64_t* __restrict__ in, unsigned shift,
                                                  unsigned* __restrict__ gh,
                                                  const unsigned* __restrict__ nsyn){
  __shared__ unsigned h[256];
  unsigned t = threadIdx.x;
  unsigned Un = nsyn[0];
  size_t base = (size_t)blockIdx.x * TILE;
  if (base >= (size_t)Un){
    gh[t * NTILES + blockIdx.x] = (t == 255u) ? (unsigned)TILE : 0u;
    return;
  }
  h[t] = 0; __syncthreads();
  #pragma unroll
  for (int r = 0; r < WPT; r++){
    unsigned i = (unsigned)(base + (size_t)r*256 + t);
    uint64_t e = (i < Un) ? in[i] : SENT;
    atomicAdd(&h[(unsigned)((e >> shift) & 0xFF)], 1u);
  }
  __syncthreads();
  gh[t * NTILES + blockIdx.x] = h[t];
}

// Row scan: block d turns gh[d][*] into exclusive tile prefixes + digit total.
// Blocked per-thread ownership + ONE blockScan (2 syncthreads instead of 10).
__global__ __launch_bounds__(256) void k_scanrows(unsigned* __restrict__ gh,
                                                  unsigned* __restrict__ dtot){
  __shared__ unsigned lw[4];
  unsigned d = blockIdx.x, t = threadIdx.x;
  unsigned rowbase = d * NTILES;
  unsigned vals[SR_CH];
  unsigned s = 0;
  #pragma unroll
  for (int k = 0; k < SR_CH; k++){
    unsigned i = t * SR_CH + (unsigned)k;
    vals[k] = (i < NTILES) ? gh[rowbase + i] : 0u;
    s += vals[k];
  }
  unsigned tot;
  unsigned carry = blockScanExcl(s, t, lw, &tot);
  #pragma unroll
  for (int k = 0; k < SR_CH; k++){
    unsigned i = t * SR_CH + (unsigned)k;
    if (i < NTILES){ gh[rowbase + i] = carry; carry += vals[k]; }
  }
  if (t == 0) dtot[d] = tot;
}

// Tiny: scan the 256 digit totals of the high byte of ~v, find the cut digit
// c = smallest d with cum(0..d) >= R_N, and write M = cum(0..c). The entire
// bin c is kept, so kept count M in [R_N, R_N + bin_c].
__global__ __launch_bounds__(256) void k_cut(const unsigned* __restrict__ dtot,
                                             unsigned* __restrict__ mvar){
  __shared__ unsigned lw[4];
  unsigned t = threadIdx.x;
  unsigned v = dtot[t];
  unsigned tot;
  unsigned excl = blockScanExcl(v, t, lw, &tot);
  unsigned incl = excl + v;
  if (excl < R_N && incl >= R_N) mvar[0] = incl;
}

// ---- LDS-staged stable radix scatter -------------------------------------
// Phase A: per-wave stable ranks. Phase B: block digit scan -> bases.
// Phase C: stage tile in LDS ordered by (digit, pos). Phase D: coalesced
// runs per digit to global.
// MODE 0: plain pass over the full NPAD array (key sort).
// MODE 1: M-mode (value phase): synthesize SENT for i >= nsyn[0]; write only
//         dest < mskip[0]. Real elements provably land at dest < M and
//         synthesized sentinels at dest >= M, so no sentinel is ever stored.
// MODE 2: M-mode final: emit output rows for dest < R_N.
template <int MODE>
__device__ __forceinline__ void scatter_body(const uint64_t* __restrict__ in,
                                             uint64_t* __restrict__ out,
                                             float* __restrict__ fout,
                                             unsigned shift,
                                             const unsigned* __restrict__ gh,
                                             const unsigned* __restrict__ dtot,
                                             const unsigned* __restrict__ nsyn,
                                             const unsigned* __restrict__ mskip){
  unsigned Un = 0u, M = 0u;
  if (MODE != 0){
    Un = nsyn[0]; M = mskip[0];
    if ((unsigned)blockIdx.x * TILE >= Un && M <= Un) return;
  }
  __shared__ unsigned wrun[4*256];
  __shared__ unsigned gput[256];
  __shared__ unsigned lw[4];
  __shared__ uint64_t stage[TILE];       // 32 KB
  unsigned t = threadIdx.x, lane = t & 63u, w = t >> 6;
  wrun[t] = 0; wrun[256+t] = 0; wrun[512+t] = 0; wrun[768+t] = 0;
  __syncthreads();
  uint64_t ltm = (lane == 0) ? 0ull : (~0ull >> (64u - lane));
  uint64_t elems[WPT]; unsigned rnk[WPT]; unsigned dg[WPT];
  size_t base = (size_t)blockIdx.x * TILE + (size_t)w * (TILE/4);
  #pragma unroll
  for (int r = 0; r < WPT; r++){
    unsigned idx = (unsigned)(base + (size_t)r*64) + lane;
    uint64_t e;
    if (MODE != 0) e = (idx < Un) ? in[idx] : SENT;
    else           e = in[idx];
    elems[r] = e;
    unsigned d = (unsigned)((e >> shift) & 0xFF);
    uint64_t m = ~0ull;
    #pragma unroll
    for (int b = 0; b < 8; b++){
      uint64_t bb = __ballot((d >> b) & 1u);
      m &= ((d >> b) & 1u) ? bb : ~bb;
    }
    unsigned rr   = (unsigned)__popcll(m & ltm);
    unsigned prev = wrun[w*256 + d];
    __builtin_amdgcn_wave_barrier();
    if (rr == 0) wrun[w*256 + d] = prev + (unsigned)__popcll(m);
    __builtin_amdgcn_wave_barrier();
    rnk[r] = prev + rr;
    dg[r]  = d;
  }
  __syncthreads();
  {
    unsigned d = t;
    unsigned c0 = wrun[d], c1 = wrun[256+d], c2 = wrun[512+d], c3 = wrun[768+d];
    unsigned cnt = c0 + c1 + c2 + c3;
    unsigned tot;
    unsigned ldig  = blockScanExcl(cnt, t, lw, &tot);       // local digit start
    unsigned tot2;
    unsigned dbase = blockScanExcl(dtot[d], t, lw, &tot2);  // global digit base
    gput[d] = dbase + gh[d * NTILES + blockIdx.x] - ldig;
    wrun[d]       = ldig;
    wrun[256 + d] = ldig + c0;
    wrun[512 + d] = ldig + c0 + c1;
    wrun[768 + d] = ldig + c0 + c1 + c2;
  }
  __syncthreads();
  #pragma unroll
  for (int r = 0; r < WPT; r++)
    stage[ wrun[w*256 + dg[r]] + rnk[r] ] = elems[r];
  __syncthreads();
  #pragma unroll
  for (int r = 0; r < WPT; r++){
    unsigned j = (unsigned)r * 256u + t;
    uint64_t e = stage[j];
    unsigned d = (unsigned)((e >> shift) & 0xFF);
    unsigned dest = gput[d] + j;
    if (MODE == 2){
      if (dest < R_N){
        uint32_t key = (uint32_t)(e >> 32);
        fout[2u*dest]        = (float)(key >> 12);
        fout[2u*dest + 1u]   = (float)(key & 4095u);
        fout[2u*R_N + dest]  = __uint_as_float(~(uint32_t)e);
      }
    } else if (MODE == 1){
      if (dest < M) out[dest] = e;
    } else {
      out[dest] = e;
    }
  }
}

// zclr: optional per-block zero of a lookback buffer for the NEXT kernel
// (workspace is re-poisoned between runs, so explicit zeroing is mandatory).
__global__ __launch_bounds__(256) void k_scatter(const uint64_t* __restrict__ in,
                                                 uint64_t* __restrict__ out,
                                                 unsigned shift,
                                                 const unsigned* __restrict__ gh,
                                                 const unsigned* __restrict__ dtot,
                                                 unsigned* __restrict__ zclr){
  if (zclr != nullptr && threadIdx.x == 0u) zclr[blockIdx.x] = 0u;
  scatter_body<0>(in, out, nullptr, shift, gh, dtot, nullptr, nullptr);
}

__global__ __launch_bounds__(256) void k_scatter_m(const uint64_t* __restrict__ in,
                                                   uint64_t* __restrict__ out,
                                                   unsigned shift,
                                                   const unsigned* __restrict__ gh,
                                                   const unsigned* __restrict__ dtot,
                                                   const unsigned* __restrict__ nsyn,
                                                   const unsigned* __restrict__ mskip){
  scatter_body<1>(in, out, nullptr, shift, gh, dtot, nsyn, mskip);
}

__global__ __launch_bounds__(256) void k_scatter_out(const uint64_t* __restrict__ in,
                                                     float* __restrict__ fout,
                                                     unsigned shift,
                                                     const unsigned* __restrict__ gh,
                                                     const unsigned* __restrict__ dtot,
                                                     const unsigned* __restrict__ nsyn){
  scatter_body<2>(in, nullptr, fout, shift, gh, dtot, nsyn, nsyn);
}

// Fused coalesce: head detection + decoupled-lookback prefix of head counts
// + in-order segmented sum, in ONE pass over the sorted array.
// lb[b] packs status(2b)|count(30b): 0=unpublished, 1=aggregate, 2=inclusive.
// Blocks dispatch in ID order and all 1076 are co-resident (tiny LDS), so
// spinning on lower-ID blocks is deadlock-free. Windowed 64-wide lookback:
// one coalesced load covers 64 predecessors.
__global__ __launch_bounds__(256) void k_coalesce(const uint64_t* __restrict__ in,
                                                  uint64_t* __restrict__ out,
                                                  unsigned* __restrict__ lb,
                                                  unsigned* __restrict__ utot){
  __shared__ unsigned wrc[64];
  __shared__ unsigned woffs[64];
  __shared__ unsigned hb;
  unsigned b = blockIdx.x, t = threadIdx.x, lane = t & 63u, w = t >> 6;
  size_t base = (size_t)b * TILE;
  // ---- flag pass: per-thread 16 head flags; per-(round,wave) counts ----
  unsigned flags = 0u;
  #pragma unroll
  for (int r = 0; r < WPT; r++){
    size_t p = base + (size_t)r*256 + t;
    uint64_t e = in[p];
    uint32_t k = (uint32_t)(e >> 32);
    uint32_t kp = (uint32_t)__shfl_up((int)k, 1, 64);
    if (lane == 0u) kp = (p == 0) ? 0u : (uint32_t)(in[p-1] >> 32);
    bool head = ((p == 0) || (kp != k)) && ((uint32_t)e != PAD_VAL);
    flags |= (head ? 1u : 0u) << r;
    unsigned long long m = __ballot(head);
    if (lane == 0u) wrc[(unsigned)r*4u + w] = (unsigned)__popcll(m);
  }
  __syncthreads();
  // ---- wave 0: block scan of 64 group counts + lookback ----
  if (w == 0u){
    unsigned v = wrc[lane];
    unsigned x = v;
    #pragma unroll
    for (int off = 1; off < 64; off <<= 1){
      unsigned y = __shfl_up(x, off, 64);
      if (lane >= (unsigned)off) x += y;
    }
    woffs[lane] = x - v;                          // exclusive group offsets
    unsigned cnt = (unsigned)__shfl((int)x, 63);  // block head total
    if (lane == 0u)
      __hip_atomic_store(&lb[b], ((b == 0u) ? (2u<<30) : (1u<<30)) | cnt,
                         __ATOMIC_RELEASE, __HIP_MEMORY_SCOPE_AGENT);
    unsigned run = 0u;
    if (b > 0u){
      int p0 = (int)b - 1;
      for (;;){
        int idx = p0 - (int)lane;
        unsigned v2 = (idx >= 0)
          ? __hip_atomic_load(&lb[idx], __ATOMIC_ACQUIRE, __HIP_MEMORY_SCOPE_AGENT)
          : (2u << 30);
        if (__ballot((v2 >> 30) == 0u)){ __builtin_amdgcn_s_sleep(1); continue; }
        unsigned long long im = __ballot((v2 >> 30) == 2u);
        unsigned cv = v2 & 0x3FFFFFFFu;
        unsigned contrib;
        bool fin = (im != 0ull);
        if (fin){
          unsigned li = (unsigned)__ffsll((long long)im) - 1u;  // nearest inclusive
          contrib = (lane <= li) ? cv : 0u;
        } else {
          contrib = cv;
        }
        #pragma unroll
        for (int off = 1; off < 64; off <<= 1)
          contrib += (unsigned)__shfl_xor((int)contrib, off, 64);
        run += contrib;
        if (fin) break;
        p0 -= 64;
      }
      if (lane == 0u)
        __hip_atomic_store(&lb[b], (2u<<30) | (run + cnt),
                           __ATOMIC_RELEASE, __HIP_MEMORY_SCOPE_AGENT);
    }
    if (lane == 0u){
      hb = run;
      if (b == (unsigned)(NTILES - 1)) utot[0] = run + cnt;
    }
  }
  __syncthreads();
  unsigned hbase = hb;
  // ---- walk & emit (identical accumulation order to segment_sum) ----
  #pragma unroll
  for (int r = 0; r < WPT; r++){
    bool f = ((flags >> r) & 1u) != 0u;
    unsigned long long m = __ballot(f);
    if (f){
      size_t p = base + (size_t)r*256 + t;
      uint64_t e0 = in[p];
      uint32_t k = (uint32_t)(e0 >> 32);
      unsigned long long ltm = (lane == 0u) ? 0ull : (~0ull >> (64u - lane));
      unsigned rank = woffs[(unsigned)r*4u + w] + (unsigned)__popcll(m & ltm);
      float s = __uint_as_float((uint32_t)e0);
      size_t q = p + 1;
      while (q < NPAD){
        uint64_t e = in[q];
        if ((uint32_t)(e >> 32) != k) break;
        uint32_t vb = (uint32_t)e;
        if (vb == PAD_VAL) break;
        s += __uint_as_float(vb);
        q++;
      }
      out[hbase + rank] = ((uint64_t)k << 32) | (uint64_t)(uint32_t)(~__float_as_uint(s));
    }
  }
}

extern "C" void kernel_launch(void* const* d_in, const int* in_sizes, int n_in,
                              void* d_out, int out_size, void* d_ws, size_t ws_size,
                              hipStream_t stream) {
  const int*   sidx = (const int*)d_in[0];
  const int*   ridx = (const int*)d_in[1];
  const float* rval = (const float*)d_in[2];
  const float* grad = (const float*)d_in[3];
  float* out = (float*)d_out;

  uint64_t* A0   = (uint64_t*)d_ws;                       // 35.3 MB
  uint64_t* A1   = A0 + NPAD;                             // 35.3 MB
  unsigned* gh   = (unsigned*)(A1 + NPAD);                // 1.1 MB
  unsigned* dtot = gh + 256 * NTILES;                     // 1 KB
  unsigned* lbuf = dtot + 256;                            // 4.3 KB (lookback)
  unsigned* utot = lbuf + NTILES;                         // 4 B
  unsigned* mvar = utot + 1;                              // 4 B

  // Build + pass-1 key hist fused (LDS histogram only).
  k_build<<<NTILES, 256, 0, stream>>>(sidx, ridx, rval, grad, A0, gh);

  // Stable key sort: 24 bits, 3 x 8-bit passes. A0->A1->A0->A1.
  // The 3rd scatter also zeroes the coalesce lookback buffer.
  k_scanrows<<<256,    256, 0, stream>>>(gh, dtot);
  k_scatter <<<NTILES, 256, 0, stream>>>(A0, A1, 32, gh, dtot, nullptr);
  k_hist    <<<NTILES, 256, 0, stream>>>(A1, 40, gh);
  k_scanrows<<<256,    256, 0, stream>>>(gh, dtot);
  k_scatter <<<NTILES, 256, 0, stream>>>(A1, A0, 40, gh, dtot, nullptr);
  k_hist    <<<NTILES, 256, 0, stream>>>(A0, 48, gh);
  k_scanrows<<<256,    256, 0, stream>>>(gh, dtot);
  k_scatter <<<NTILES, 256, 0, stream>>>(A0, A1, 48, gh, dtot, lbuf);

  // Fused coalesce (headcount + lookback scan + segsum in one pass).
  // Candidates written dense & key-ascending into A0[0, U).
  k_coalesce<<<NTILES, 256, 0, stream>>>(A1, A0, lbuf, utot);

  // Select: histogram high byte of ~v, find cut, stable-compact the kept
  // M ~= R_N + one bin elements into A1[0, M). No tail fill ever happens.
  k_hist_syn <<<NTILES, 256, 0, stream>>>(A0, 24, gh, utot);
  k_scanrows <<<256,    256, 0, stream>>>(gh, dtot);
  k_cut      <<<1,      256, 0, stream>>>(dtot, mvar);
  k_scatter_m<<<NTILES, 256, 0, stream>>>(A0, A1, 24, gh, dtot, utot, mvar);

  // Stable value sort over only M elements: 4 x 8-bit LSD passes,
  // final pass fused with output emission. A1->A0->A1->A0->out.
  k_hist_syn <<<NTILES, 256, 0, stream>>>(A1, 0, gh, mvar);
  k_scanrows <<<256,    256, 0, stream>>>(gh, dtot);
  k_scatter_m<<<NTILES, 256, 0, stream>>>(A1, A0, 0, gh, dtot, mvar, mvar);
  k_hist_syn <<<NTILES, 256, 0, stream>>>(A0, 8, gh, mvar);
  k_scanrows <<<256,    256, 0, stream>>>(gh, dtot);
  k_scatter_m<<<NTILES, 256, 0, stream>>>(A0, A1, 8, gh, dtot, mvar, mvar);
  k_hist_syn <<<NTILES, 256, 0, stream>>>(A1, 16, gh, mvar);
  k_scanrows <<<256,    256, 0, stream>>>(gh, dtot);
  k_scatter_m<<<NTILES, 256, 0, stream>>>(A1, A0, 16, gh, dtot, mvar, mvar);
  k_hist_syn   <<<NTILES, 256, 0, stream>>>(A0, 24, gh, mvar);
  k_scanrows   <<<256,    256, 0, stream>>>(gh, dtot);
  k_scatter_out<<<NTILES, 256, 0, stream>>>(A0, out, 24, gh, dtot, mvar);
}

// Round 6
// 412.108 us; speedup vs baseline: 1.1274x; 1.1274x over previous
//
#include <hip/hip_runtime.h>
#include <stdint.h>

#define CDIM   4096
#define S_N    3355443
#define R_N    1048576
#define N1     (S_N + R_N)                 // 4404019 contributions
#define TILE   4096
#define WPT    (TILE / 256)                // 16 elements per thread
#define NTILES ((N1 + TILE - 1) / TILE)    // 1076
#define NPAD   (NTILES * TILE)             // 4407296
#define NSB    (NPAD / 256)                // 17216
#define SR_CH  ((NTILES + 255) / 256)      // 5 row entries per thread in scanrows
#define PAD_KEY 0xFFFFFFu
#define PAD_VAL 0xFFFFFFFFu                // impossible value bits (sums are >= +0)
#define SENT  (((uint64_t)PAD_KEY << 32) | (uint64_t)PAD_VAL)
#define ADJF  ((float)(1.0 - (3355443.0 / 16777216.0) * (1.0 - 0.95)))

// Exclusive block-wide scan over 256 threads (4 waves). Contains syncthreads.
static __device__ __forceinline__ unsigned blockScanExcl(unsigned v, unsigned t,
                                                         unsigned* lw, unsigned* tot){
  unsigned lane = t & 63u, w = t >> 6;
  unsigned x = v;
  #pragma unroll
  for (int off = 1; off < 64; off <<= 1){
    unsigned y = __shfl_up(x, off, 64);
    if (lane >= (unsigned)off) x += y;
  }
  if (lane == 63u) lw[w] = x;
  __syncthreads();
  unsigned woff = 0;
  for (unsigned i = 0; i < w; i++) woff += lw[i];
  *tot = lw[0] + lw[1] + lw[2] + lw[3];
  __syncthreads();
  return x + woff - v;
}

// Recompute element idx of the contribution array from the raw inputs.
// Samples first, then decayed buffer entries, then padding -> stable sort
// preserves segment_sum's accumulation order exactly.
static __device__ __forceinline__ uint64_t make_elem(unsigned i,
                                                     const int* __restrict__ sidx,
                                                     const int* __restrict__ ridx,
                                                     const float* __restrict__ rval,
                                                     const float* __restrict__ grad){
  uint32_t key, vb;
  if (i < S_N){
    key = (uint32_t)sidx[i];
    vb  = __float_as_uint(fabsf(grad[i]));
  } else if (i < N1){
    unsigned j = i - S_N;
    int2 rc = ((const int2* __restrict__)ridx)[j];
    key = (uint32_t)(rc.x * CDIM + rc.y);
    vb = __float_as_uint(ADJF * rval[j]);
  } else {
    key = PAD_KEY; vb = PAD_VAL;
  }
  return ((uint64_t)key << 32) | (uint64_t)vb;
}

// Pass-1 key histogram straight from the inputs (key low byte only: needs
// sidx + ridx.y, NOT grad/rval, and writes no element array).
__global__ __launch_bounds__(256) void k_hist0(const int* __restrict__ sidx,
                                               const int* __restrict__ ridx,
                                               unsigned* __restrict__ gh){
  __shared__ unsigned h[256];
  unsigned t = threadIdx.x;
  h[t] = 0; __syncthreads();
  size_t base = (size_t)blockIdx.x * TILE;
  #pragma unroll
  for (int r = 0; r < WPT; r++){
    unsigned i = (unsigned)(base + (size_t)r*256 + t);
    unsigned kb;
    if (i < S_N)       kb = ((uint32_t)sidx[i]) & 0xFFu;
    else if (i < N1)   kb = ((uint32_t)ridx[2u*(i - S_N) + 1u]) & 0xFFu; // col low byte
    else               kb = 0xFFu;                                       // PAD_KEY & 0xFF
    atomicAdd(&h[kb], 1u);         // LDS atomic only
  }
  __syncthreads();
  gh[t * NTILES + blockIdx.x] = h[t];
}

// Per-tile 256-bin histogram of digit (e >> shift) & 0xFF. Layout [digit][tile].
__global__ __launch_bounds__(256) void k_hist(const uint64_t* __restrict__ in, unsigned shift,
                                              unsigned* __restrict__ gh){
  __shared__ unsigned h[256];
  unsigned t = threadIdx.x;
  h[t] = 0; __syncthreads();
  size_t base = (size_t)blockIdx.x * TILE;
  #pragma unroll
  for (int r = 0; r < WPT; r++){
    uint64_t e = in[base + (size_t)r*256 + t];
    atomicAdd(&h[(unsigned)((e >> shift) & 0xFF)], 1u);
  }
  __syncthreads();
  gh[t * NTILES + blockIdx.x] = h[t];
}

// Histogram with sentinel synthesis for i >= nsyn[0]: elements beyond the
// live prefix are counted as digit 255 without touching memory. Tail tiles
// write their (constant) column and return.
__global__ __launch_bounds__(256) void k_hist_syn(const uint64_t* __restrict__ in, unsigned shift,
                                                  unsigned* __restrict__ gh,
                                                  const unsigned* __restrict__ nsyn){
  __shared__ unsigned h[256];
  unsigned t = threadIdx.x;
  unsigned Un = nsyn[0];
  size_t base = (size_t)blockIdx.x * TILE;
  if (base >= (size_t)Un){
    gh[t * NTILES + blockIdx.x] = (t == 255u) ? (unsigned)TILE : 0u;
    return;
  }
  h[t] = 0; __syncthreads();
  #pragma unroll
  for (int r = 0; r < WPT; r++){
    unsigned i = (unsigned)(base + (size_t)r*256 + t);
    uint64_t e = (i < Un) ? in[i] : SENT;
    atomicAdd(&h[(unsigned)((e >> shift) & 0xFF)], 1u);
  }
  __syncthreads();
  gh[t * NTILES + blockIdx.x] = h[t];
}

// Row scan: block d turns gh[d][*] into exclusive tile prefixes + digit total.
// Blocked per-thread ownership + ONE blockScan (2 syncthreads instead of 10).
__global__ __launch_bounds__(256) void k_scanrows(unsigned* __restrict__ gh,
                                                  unsigned* __restrict__ dtot){
  __shared__ unsigned lw[4];
  unsigned d = blockIdx.x, t = threadIdx.x;
  unsigned rowbase = d * NTILES;
  unsigned vals[SR_CH];
  unsigned s = 0;
  #pragma unroll
  for (int k = 0; k < SR_CH; k++){
    unsigned i = t * SR_CH + (unsigned)k;
    vals[k] = (i < NTILES) ? gh[rowbase + i] : 0u;
    s += vals[k];
  }
  unsigned tot;
  unsigned carry = blockScanExcl(s, t, lw, &tot);
  #pragma unroll
  for (int k = 0; k < SR_CH; k++){
    unsigned i = t * SR_CH + (unsigned)k;
    if (i < NTILES){ gh[rowbase + i] = carry; carry += vals[k]; }
  }
  if (t == 0) dtot[d] = tot;
}

// ---- LDS-staged stable radix scatter -------------------------------------
// Phase A: per-wave stable ranks. Phase B: block digit scan -> bases.
// Phase C: stage tile in LDS ordered by (digit, pos). Phase D: coalesced
// runs per digit to global.
// MODE 0: plain pass over the full NPAD array.
// MODE 1: M-mode (value LSD): synthesize SENT for i >= nsyn[0]; write only
//         dest < mskip[0].
// MODE 2: M-mode final: emit output rows for dest < R_N.
// MODE 3: build-recompute: elements recomputed from raw inputs (key pass 1,
//         no element-array read; removes the A0 round-trip).
// MODE 4: compact with FUSED CUT: M computed in phase B from the dtot scan
//         (identical arithmetic to the old k_cut); block 0 persists mvar.
template <int MODE>
__device__ __forceinline__ void scatter_body(const uint64_t* __restrict__ in,
                                             uint64_t* __restrict__ out,
                                             float* __restrict__ fout,
                                             unsigned shift,
                                             const unsigned* __restrict__ gh,
                                             const unsigned* __restrict__ dtot,
                                             const unsigned* __restrict__ nsyn,
                                             const unsigned* __restrict__ mskip,
                                             const int* __restrict__ sidx,
                                             const int* __restrict__ ridx,
                                             const float* __restrict__ rval,
                                             const float* __restrict__ grad,
                                             unsigned* __restrict__ mout){
  unsigned Un = 0u, M = 0u;
  if (MODE == 1 || MODE == 2 || MODE == 4){
    Un = nsyn[0];
    if (MODE != 4){
      M = mskip[0];
      if ((unsigned)blockIdx.x * TILE >= Un && M <= Un) return;
    }
  }
  __shared__ unsigned wrun[4*256];
  __shared__ unsigned gput[256];
  __shared__ unsigned lw[4];
  __shared__ unsigned cutm;
  __shared__ uint64_t stage[TILE];       // 32 KB
  unsigned t = threadIdx.x, lane = t & 63u, w = t >> 6;
  wrun[t] = 0; wrun[256+t] = 0; wrun[512+t] = 0; wrun[768+t] = 0;
  __syncthreads();
  uint64_t ltm = (lane == 0) ? 0ull : (~0ull >> (64u - lane));
  uint64_t elems[WPT]; unsigned rnk[WPT]; unsigned dg[WPT];
  size_t base = (size_t)blockIdx.x * TILE + (size_t)w * (TILE/4);
  #pragma unroll
  for (int r = 0; r < WPT; r++){
    unsigned idx = (unsigned)(base + (size_t)r*64) + lane;
    uint64_t e;
    if (MODE == 3)      e = make_elem(idx, sidx, ridx, rval, grad);
    else if (MODE != 0) e = (idx < Un) ? in[idx] : SENT;
    else                e = in[idx];
    elems[r] = e;
    unsigned d = (unsigned)((e >> shift) & 0xFF);
    uint64_t m = ~0ull;
    #pragma unroll
    for (int b = 0; b < 8; b++){
      uint64_t bb = __ballot((d >> b) & 1u);
      m &= ((d >> b) & 1u) ? bb : ~bb;
    }
    unsigned rr   = (unsigned)__popcll(m & ltm);
    unsigned prev = wrun[w*256 + d];
    __builtin_amdgcn_wave_barrier();
    if (rr == 0) wrun[w*256 + d] = prev + (unsigned)__popcll(m);
    __builtin_amdgcn_wave_barrier();
    rnk[r] = prev + rr;
    dg[r]  = d;
  }
  __syncthreads();
  {
    unsigned d = t;
    unsigned c0 = wrun[d], c1 = wrun[256+d], c2 = wrun[512+d], c3 = wrun[768+d];
    unsigned cnt = c0 + c1 + c2 + c3;
    unsigned tot;
    unsigned ldig  = blockScanExcl(cnt, t, lw, &tot);       // local digit start
    unsigned tot2;
    unsigned dbase = blockScanExcl(dtot[d], t, lw, &tot2);  // global digit base
    if (MODE == 4){
      unsigned incl = dbase + dtot[d];                      // == k_cut arithmetic
      if (dbase < R_N && incl >= R_N) cutm = incl;
    }
    gput[d] = dbase + gh[d * NTILES + blockIdx.x] - ldig;
    wrun[d]       = ldig;
    wrun[256 + d] = ldig + c0;
    wrun[512 + d] = ldig + c0 + c1;
    wrun[768 + d] = ldig + c0 + c1 + c2;
  }
  __syncthreads();
  if (MODE == 4){
    M = cutm;
    if (blockIdx.x == 0u && t == 0u) mout[0] = M;           // for later kernels
  }
  #pragma unroll
  for (int r = 0; r < WPT; r++)
    stage[ wrun[w*256 + dg[r]] + rnk[r] ] = elems[r];
  __syncthreads();
  #pragma unroll
  for (int r = 0; r < WPT; r++){
    unsigned j = (unsigned)r * 256u + t;
    uint64_t e = stage[j];
    unsigned d = (unsigned)((e >> shift) & 0xFF);
    unsigned dest = gput[d] + j;
    if (MODE == 2){
      if (dest < R_N){
        uint32_t key = (uint32_t)(e >> 32);
        fout[2u*dest]        = (float)(key >> 12);
        fout[2u*dest + 1u]   = (float)(key & 4095u);
        fout[2u*R_N + dest]  = __uint_as_float(~(uint32_t)e);
      }
    } else if (MODE == 1 || MODE == 4){
      if (dest < M) out[dest] = e;
    } else {
      out[dest] = e;
    }
  }
}

__global__ __launch_bounds__(256) void k_scatter(const uint64_t* __restrict__ in,
                                                 uint64_t* __restrict__ out,
                                                 unsigned shift,
                                                 const unsigned* __restrict__ gh,
                                                 const unsigned* __restrict__ dtot){
  scatter_body<0>(in, out, nullptr, shift, gh, dtot, nullptr, nullptr,
                  nullptr, nullptr, nullptr, nullptr, nullptr);
}

__global__ __launch_bounds__(256) void k_scatter_b(const int* __restrict__ sidx,
                                                   const int* __restrict__ ridx,
                                                   const float* __restrict__ rval,
                                                   const float* __restrict__ grad,
                                                   uint64_t* __restrict__ out,
                                                   unsigned shift,
                                                   const unsigned* __restrict__ gh,
                                                   const unsigned* __restrict__ dtot){
  scatter_body<3>(nullptr, out, nullptr, shift, gh, dtot, nullptr, nullptr,
                  sidx, ridx, rval, grad, nullptr);
}

__global__ __launch_bounds__(256) void k_scatter_m(const uint64_t* __restrict__ in,
                                                   uint64_t* __restrict__ out,
                                                   unsigned shift,
                                                   const unsigned* __restrict__ gh,
                                                   const unsigned* __restrict__ dtot,
                                                   const unsigned* __restrict__ nsyn,
                                                   const unsigned* __restrict__ mskip){
  scatter_body<1>(in, out, nullptr, shift, gh, dtot, nsyn, mskip,
                  nullptr, nullptr, nullptr, nullptr, nullptr);
}

__global__ __launch_bounds__(256) void k_scatter_mc(const uint64_t* __restrict__ in,
                                                    uint64_t* __restrict__ out,
                                                    unsigned shift,
                                                    const unsigned* __restrict__ gh,
                                                    const unsigned* __restrict__ dtot,
                                                    const unsigned* __restrict__ nsyn,
                                                    unsigned* __restrict__ mout){
  scatter_body<4>(in, out, nullptr, shift, gh, dtot, nsyn, nullptr,
                  nullptr, nullptr, nullptr, nullptr, mout);
}

__global__ __launch_bounds__(256) void k_scatter_out(const uint64_t* __restrict__ in,
                                                     float* __restrict__ fout,
                                                     unsigned shift,
                                                     const unsigned* __restrict__ gh,
                                                     const unsigned* __restrict__ dtot,
                                                     const unsigned* __restrict__ nsyn){
  scatter_body<2>(in, nullptr, fout, shift, gh, dtot, nsyn, nsyn,
                  nullptr, nullptr, nullptr, nullptr, nullptr);
}

// Count real segment heads per 256-elem block (phantom pad-head excluded so
// the scanned total is the exact candidate count U).
__global__ __launch_bounds__(256) void k_headcount(const uint64_t* __restrict__ in,
                                                   unsigned* __restrict__ hcnt){
  __shared__ unsigned wc[4];
  unsigned t = threadIdx.x, lane = t & 63u, w = t >> 6;
  size_t p = (size_t)blockIdx.x * 256 + t;
  uint64_t e = in[p];
  uint32_t k = (uint32_t)(e >> 32);
  bool head = ((p == 0) || ((uint32_t)(in[p-1] >> 32) != k)) && ((uint32_t)e != PAD_VAL);
  uint64_t m = __ballot(head);
  if (lane == 0) wc[w] = (unsigned)__popcll(m);
  __syncthreads();
  if (t == 0) hcnt[blockIdx.x] = wc[0] + wc[1] + wc[2] + wc[3];
}

// Fast single-block scan of NSB head counts via u16 LDS staging; writes U.
__global__ __launch_bounds__(256) void k_scanheads(unsigned* __restrict__ hcnt,
                                                   unsigned* __restrict__ utot){
  __shared__ unsigned short buf[NSB];    // counts <= 256 fit u16; 34.4 KB
  __shared__ unsigned lw[4];
  unsigned t = threadIdx.x;
  for (unsigned i = t; i < NSB; i += 256) buf[i] = (unsigned short)hcnt[i];
  __syncthreads();
  const unsigned CH = (NSB + 255) / 256; // 68 elems/thread, blocked
  unsigned s = 0;
  for (unsigned k = 0; k < CH; k++){
    unsigned i = t * CH + k;
    if (i < NSB) s += buf[i];
  }
  unsigned tot;
  unsigned carry = blockScanExcl(s, t, lw, &tot);
  for (unsigned k = 0; k < CH; k++){
    unsigned i = t * CH + k;
    if (i < NSB){ unsigned v = buf[i]; hcnt[i] = carry; carry += v; }
  }
  if (t == 0) utot[0] = tot;
}

// In-order segmented sum: head thread walks its key segment sequentially
// (original contribution order thanks to the stable key sort) -> fp32 sum is
// bit-identical to segment_sum. Candidates written dense, key-ascending.
// One thread per ELEMENT: the serial walks stay latency-hidden by TLP.
__global__ __launch_bounds__(256) void k_segsum(const uint64_t* __restrict__ in,
                                                uint64_t* __restrict__ out,
                                                const unsigned* __restrict__ hbase){
  __shared__ unsigned wc[4], woffs[4];
  unsigned t = threadIdx.x, lane = t & 63u, w = t >> 6;
  size_t p = (size_t)blockIdx.x * 256 + t;
  uint64_t e0 = in[p];
  uint32_t k = (uint32_t)(e0 >> 32);
  bool head = ((p == 0) || ((uint32_t)(in[p-1] >> 32) != k)) && ((uint32_t)e0 != PAD_VAL);
  uint64_t m = __ballot(head);
  if (lane == 0) wc[w] = (unsigned)__popcll(m);
  __syncthreads();
  if (t == 0){ unsigned a = 0; for (int i = 0; i < 4; i++){ woffs[i] = a; a += wc[i]; } }
  __syncthreads();
  if (head){
    uint64_t ltm = (lane == 0) ? 0ull : (~0ull >> (64u - lane));
    unsigned rank = (unsigned)__popcll(m & ltm);
    unsigned oidx = hbase[blockIdx.x] + woffs[w] + rank;
    float s = __uint_as_float((uint32_t)e0);
    size_t q = p + 1;
    while (q < NPAD){
      uint64_t e = in[q];
      if ((uint32_t)(e >> 32) != k) break;
      uint32_t vb = (uint32_t)e;
      if (vb == PAD_VAL) break;
      s += __uint_as_float(vb);
      q++;
    }
    out[oidx] = ((uint64_t)k << 32) | (uint64_t)(uint32_t)(~__float_as_uint(s));
  }
}

extern "C" void kernel_launch(void* const* d_in, const int* in_sizes, int n_in,
                              void* d_out, int out_size, void* d_ws, size_t ws_size,
                              hipStream_t stream) {
  const int*   sidx = (const int*)d_in[0];
  const int*   ridx = (const int*)d_in[1];
  const float* rval = (const float*)d_in[2];
  const float* grad = (const float*)d_in[3];
  float* out = (float*)d_out;

  uint64_t* A0   = (uint64_t*)d_ws;                       // 35.3 MB
  uint64_t* A1   = A0 + NPAD;                             // 35.3 MB
  unsigned* gh   = (unsigned*)(A1 + NPAD);                // 1.1 MB
  unsigned* dtot = gh + 256 * NTILES;                     // 1 KB
  unsigned* hcnt = dtot + 256;                            // 67 KB
  unsigned* utot = hcnt + NSB;                            // 4 B
  unsigned* mvar = utot + 1;                              // 4 B

  // Stable key sort: 24 bits, 3 x 8-bit passes. Pass 1 recomputes elements
  // from the raw inputs (no element-array build/read). inputs->A1->A0->A1.
  k_hist0    <<<NTILES, 256, 0, stream>>>(sidx, ridx, gh);
  k_scanrows <<<256,    256, 0, stream>>>(gh, dtot);
  k_scatter_b<<<NTILES, 256, 0, stream>>>(sidx, ridx, rval, grad, A1, 32, gh, dtot);
  k_hist     <<<NTILES, 256, 0, stream>>>(A1, 40, gh);
  k_scanrows <<<256,    256, 0, stream>>>(gh, dtot);
  k_scatter  <<<NTILES, 256, 0, stream>>>(A1, A0, 40, gh, dtot);
  k_hist     <<<NTILES, 256, 0, stream>>>(A0, 48, gh);
  k_scanrows <<<256,    256, 0, stream>>>(gh, dtot);
  k_scatter  <<<NTILES, 256, 0, stream>>>(A0, A1, 48, gh, dtot);

  // Coalesce. Candidates written dense & key-ascending into A0[0, U).
  k_headcount<<<NSB, 256, 0, stream>>>(A1, hcnt);
  k_scanheads<<<1,   256, 0, stream>>>(hcnt, utot);
  k_segsum   <<<NSB, 256, 0, stream>>>(A1, A0, hcnt);

  // Select: histogram high byte of ~v; compact scatter computes the cut M
  // in-kernel from the dtot scan (fused k_cut) and persists mvar.
  k_hist_syn  <<<NTILES, 256, 0, stream>>>(A0, 24, gh, utot);
  k_scanrows  <<<256,    256, 0, stream>>>(gh, dtot);
  k_scatter_mc<<<NTILES, 256, 0, stream>>>(A0, A1, 24, gh, dtot, utot, mvar);

  // Stable value sort over only M elements: 4 x 8-bit LSD passes,
  // final pass fused with output emission. A1->A0->A1->A0->out.
  k_hist_syn <<<NTILES, 256, 0, stream>>>(A1, 0, gh, mvar);
  k_scanrows <<<256,    256, 0, stream>>>(gh, dtot);
  k_scatter_m<<<NTILES, 256, 0, stream>>>(A1, A0, 0, gh, dtot, mvar, mvar);
  k_hist_syn <<<NTILES, 256, 0, stream>>>(A0, 8, gh, mvar);
  k_scanrows <<<256,    256, 0, stream>>>(gh, dtot);
  k_scatter_m<<<NTILES, 256, 0, stream>>>(A0, A1, 8, gh, dtot, mvar, mvar);
  k_hist_syn <<<NTILES, 256, 0, stream>>>(A1, 16, gh, mvar);
  k_scanrows <<<256,    256, 0, stream>>>(gh, dtot);
  k_scatter_m<<<NTILES, 256, 0, stream>>>(A1, A0, 16, gh, dtot, mvar, mvar);
  k_hist_syn   <<<NTILES, 256, 0, stream>>>(A0, 24, gh, mvar);
  k_scanrows   <<<256,    256, 0, stream>>>(gh, dtot);
  k_scatter_out<<<NTILES, 256, 0, stream>>>(A0, out, 24, gh, dtot, mvar);
}